// Round 7
// baseline (329.995 us; speedup 1.0000x reference)
//
#include <hip/hip_runtime.h>
#include <math.h>

#define R_ROWS 26588
#define S_TOT  13294
#define NHEAD  8
#define NLVL   4
#define EPSF   1e-5f

typedef __attribute__((ext_vector_type(8))) short short8;
typedef __attribute__((ext_vector_type(4))) float f32x4;
typedef __attribute__((ext_vector_type(2))) float f32x2;
typedef unsigned short ushort_t;

__device__ __forceinline__ unsigned short f2bf(float f) {
    unsigned int u = __builtin_bit_cast(unsigned int, f);
    unsigned int r = (u + 0x7FFFu + ((u >> 16) & 1u)) >> 16;   // RNE
    return (unsigned short)r;
}

// ---------------------------------------------------------------------------
// All six weight transposes in ONE kernel. src f32 [K][N] -> dst bf16 [N][K].
// ---------------------------------------------------------------------------
__global__ __launch_bounds__(256) void transpose_all_kernel(
    const float* __restrict__ W_val, const float* __restrict__ W_off,
    const float* __restrict__ W_attn, const float* __restrict__ W_out,
    const float* __restrict__ W1, const float* __restrict__ W2,
    ushort_t* __restrict__ wt_val, ushort_t* __restrict__ wt_off,
    ushort_t* __restrict__ wt_attn, ushort_t* __restrict__ wt_out,
    ushort_t* __restrict__ wt_w1, ushort_t* __restrict__ wt_w2)
{
    int bid = blockIdx.x;
    const float* src; ushort_t* dst; int K, N, t;
    if (bid < 64)       { src = W_val;  dst = wt_val;  K = 256;  N = 256;  t = bid; }
    else if (bid < 128) { src = W_off;  dst = wt_off;  K = 256;  N = 256;  t = bid - 64; }
    else if (bid < 160) { src = W_attn; dst = wt_attn; K = 256;  N = 128;  t = bid - 128; }
    else if (bid < 224) { src = W_out;  dst = wt_out;  K = 256;  N = 256;  t = bid - 160; }
    else if (bid < 480) { src = W1;     dst = wt_w1;   K = 256;  N = 1024; t = bid - 224; }
    else                { src = W2;     dst = wt_w2;   K = 1024; N = 256;  t = bid - 480; }
    int nt = N / 32;
    int bn = (t % nt) * 32, bk = (t / nt) * 32;

    __shared__ ushort_t tt[32][33];
    int x = threadIdx.x & 31;
    int y = threadIdx.x >> 5;
#pragma unroll
    for (int i = 0; i < 4; ++i) {
        int k = y + i * 8;
        tt[x][k] = f2bf(src[(long)(bk + k) * N + bn + x]);
    }
    __syncthreads();
#pragma unroll
    for (int i = 0; i < 4; ++i) {
        int n = y + i * 8;
        dst[(long)(bn + n) * K + bk + x] = tt[n][x];
    }
}

// ---------------------------------------------------------------------------
// qry_bf = bf16(query), qsum_bf = bf16(query + qpos). 4 elem/thread.
// ---------------------------------------------------------------------------
__global__ __launch_bounds__(256) void addcvt_kernel(
    const float* __restrict__ q, const float* __restrict__ p,
    ushort_t* __restrict__ qry_bf, ushort_t* __restrict__ qsum_bf, int n4)
{
    int i = blockIdx.x * 256 + threadIdx.x;
    if (i >= n4) return;
    float4 a = ((const float4*)q)[i];
    float4 b = ((const float4*)p)[i];
    uint2 qa, qs;
    qa.x = (unsigned)f2bf(a.x) | ((unsigned)f2bf(a.y) << 16);
    qa.y = (unsigned)f2bf(a.z) | ((unsigned)f2bf(a.w) << 16);
    qs.x = (unsigned)f2bf(a.x + b.x) | ((unsigned)f2bf(a.y + b.y) << 16);
    qs.y = (unsigned)f2bf(a.z + b.z) | ((unsigned)f2bf(a.w + b.w) << 16);
    ((uint2*)qry_bf)[i] = qa;
    ((uint2*)qsum_bf)[i] = qs;
}

// ---------------------------------------------------------------------------
// Async triple-buffered GEMM, templated M-tile (128 or 64) x 128 N-tile, BK=32.
// MT=128: 4 waves 2x2, wave 64x64, 4 DMA/wave/stage.
// MT=64 : 4 waves 2x2, wave 32x64, 3 DMA/wave/stage (for small grids).
// XOR quad swizzle on global side; raw s_barrier + manual vmcnt pipeline.
// ---------------------------------------------------------------------------
template<int MT>
__device__ __forceinline__ void stage_ab(
    const ushort_t* __restrict__ Arow, const ushort_t* __restrict__ Brow,
    int K, int k0, ushort_t* As, ushort_t* Bs, int wave, int lane)
{
    int quadS = lane & 3;
    int rr = lane >> 2;     // 0..15
    constexpr int AI = MT / 64;   // A DMA insts per wave
#pragma unroll
    for (int inst = 0; inst < AI; ++inst) {
        int base_row = wave * (MT / 4) + inst * 16;
        int r = base_row + rr;
        int quadG = quadS ^ ((r >> 1) & 3);
        const ushort_t* gp = Arow + (long)r * K + k0 + quadG * 8;
        __builtin_amdgcn_global_load_lds(
            (const __attribute__((address_space(1))) unsigned int*)gp,
            (__attribute__((address_space(3))) unsigned int*)&As[base_row * 32],
            16, 0, 0);
    }
#pragma unroll
    for (int inst = 0; inst < 2; ++inst) {
        int base_row = wave * 32 + inst * 16;
        int r = base_row + rr;
        int quadG = quadS ^ ((r >> 1) & 3);
        const ushort_t* gp = Brow + (long)r * K + k0 + quadG * 8;
        __builtin_amdgcn_global_load_lds(
            (const __attribute__((address_space(1))) unsigned int*)gp,
            (__attribute__((address_space(3))) unsigned int*)&Bs[base_row * 32],
            16, 0, 0);
    }
}

template<int MT>
__device__ __forceinline__ void gemm_body(
    ushort_t* As, ushort_t* Bs,   // flat [3*MT*32] / [3*4096]
    const ushort_t* __restrict__ A, const ushort_t* __restrict__ Wt,
    const float* __restrict__ bias, void* __restrict__ Cv,
    int M, int N, int K, int bm, int bn, bool out_bf16, bool relu)
{
    constexpr int TBA = MT * 32;
    constexpr int TBB = 4096;
    constexpr int MFR = MT / 32;    // A frags per wave
    const int tid  = threadIdx.x;
    const int wave = tid >> 6;
    const int lane = tid & 63;
    const int l15  = lane & 15;
    const int quad = lane >> 4;
    const int wm   = (wave >> 1) * (MT / 2);
    const int wn   = (wave & 1) * 64;

    const ushort_t* Arow = A + (long)bm * K;
    const ushort_t* Brow = Wt + (long)bn * K;

    f32x4 acc[MFR][4];
#pragma unroll
    for (int i = 0; i < MFR; ++i)
#pragma unroll
        for (int j = 0; j < 4; ++j) acc[i][j] = (f32x4)0.0f;

    int aoff[MFR], boff[4];
#pragma unroll
    for (int mi = 0; mi < MFR; ++mi) {
        int r = wm + mi * 16 + l15;
        aoff[mi] = r * 32 + (quad ^ ((r >> 1) & 3)) * 8;
    }
#pragma unroll
    for (int ni = 0; ni < 4; ++ni) {
        int r = wn + ni * 16 + l15;
        boff[ni] = r * 32 + (quad ^ ((r >> 1) & 3)) * 8;
    }

    const int NT = K >> 5;
    stage_ab<MT>(Arow, Brow, K, 0, As, Bs, wave, lane);
    int cur = 0;
    for (int t = 0; t < NT; ++t) {
        int nxt = cur + 1; if (nxt == 3) nxt = 0;
        if (t + 1 < NT) {
            stage_ab<MT>(Arow, Brow, K, (t + 1) << 5,
                         As + nxt * TBA, Bs + nxt * TBB, wave, lane);
            if constexpr (MT == 128)
                asm volatile("s_waitcnt vmcnt(4)" ::: "memory");
            else
                asm volatile("s_waitcnt vmcnt(3)" ::: "memory");
        } else {
            asm volatile("s_waitcnt vmcnt(0)" ::: "memory");
        }
        asm volatile("s_barrier" ::: "memory");

        const ushort_t* Ab = As + cur * TBA;
        const ushort_t* Bb = Bs + cur * TBB;
        short8 af[MFR], bf[4];
#pragma unroll
        for (int mi = 0; mi < MFR; ++mi) af[mi] = *(const short8*)&Ab[aoff[mi]];
#pragma unroll
        for (int ni = 0; ni < 4; ++ni) bf[ni] = *(const short8*)&Bb[boff[ni]];
#pragma unroll
        for (int mi = 0; mi < MFR; ++mi)
#pragma unroll
            for (int ni = 0; ni < 4; ++ni)
                acc[mi][ni] = __builtin_amdgcn_mfma_f32_16x16x32_bf16(
                    af[mi], bf[ni], acc[mi][ni], 0, 0, 0);
        cur = nxt;
    }

#pragma unroll
    for (int mi = 0; mi < MFR; ++mi) {
#pragma unroll
        for (int r = 0; r < 4; ++r) {
            int row = bm + wm + mi * 16 + quad * 4 + r;
            if (row >= M) continue;
#pragma unroll
            for (int ni = 0; ni < 4; ++ni) {
                int col = bn + wn + ni * 16 + l15;
                float vv = acc[mi][ni][r] + bias[col];
                if (relu) vv = fmaxf(vv, 0.f);
                if (out_bf16)
                    ((ushort_t*)Cv)[(long)row * N + col] = f2bf(vv);
                else
                    ((float*)Cv)[(long)row * N + col] = vv;
            }
        }
    }
}

template<int MT, bool OUT_BF16, bool RELU>
__global__ __launch_bounds__(256) void gemm_mfma_kernel(
    const ushort_t* __restrict__ A, const ushort_t* __restrict__ Wt,
    const float* __restrict__ bias, void* __restrict__ Cv,
    int M, int N, int K)
{
    __shared__ ushort_t As[3 * MT * 32];
    __shared__ ushort_t Bs[3 * 4096];
    gemm_body<MT>(As, Bs, A, Wt, bias, Cv, M, N, K,
                  blockIdx.x * MT, blockIdx.y * 128, OUT_BF16, RELU);
}

// Combined val/off/attn projections. grid = (208, 5). MT=128.
__global__ __launch_bounds__(256) void proj_kernel(
    const ushort_t* __restrict__ qry_bf, const ushort_t* __restrict__ q_bf,
    const ushort_t* __restrict__ wt_val, const ushort_t* __restrict__ wt_off,
    const ushort_t* __restrict__ wt_attn,
    const float* __restrict__ b_val, const float* __restrict__ b_off,
    const float* __restrict__ b_attn,
    ushort_t* __restrict__ v_bf, float* __restrict__ cb, float* __restrict__ logits)
{
    __shared__ ushort_t As[3 * 4096];
    __shared__ ushort_t Bs[3 * 4096];
    int y = blockIdx.y;
    const ushort_t* A; const ushort_t* Wt; const float* bias;
    void* C; bool outbf; int N, bn;
    if (y < 2)      { A = qry_bf; Wt = wt_val;  bias = b_val;  C = v_bf;   outbf = true;  N = 256; bn = y * 128; }
    else if (y < 4) { A = q_bf;   Wt = wt_off;  bias = b_off;  C = cb;     outbf = false; N = 256; bn = (y - 2) * 128; }
    else            { A = q_bf;   Wt = wt_attn; bias = b_attn; C = logits; outbf = false; N = 128; bn = 0; }
    gemm_body<128>(As, Bs, A, Wt, bias, C, R_ROWS, N, 256, blockIdx.x * 128, bn, outbf, false);
}

// ---------------------------------------------------------------------------
// Deformable sampling + fused softmax. 4 lanes per (row,head) group; lane j
// computes level j's geometry ONCE, stashes (4 corner weights, 4 clamped
// indices) per point in padded LDS, then all lanes stream 16 points via
// broadcast ds_read_b128 (no bpermute in the hot loop).
// ---------------------------------------------------------------------------
#define DEF_BLOCKS 3328
#define DEF_CHUNK  416   // DEF_BLOCKS / 8

__global__ __launch_bounds__(256) void deform_sample_kernel(
    const ushort_t* __restrict__ v, const float* __restrict__ off,
    const float* __restrict__ logits, const float* __restrict__ vr,
    ushort_t* __restrict__ out)
{
    __shared__ float4 gw[64][17];   // 17-pad: 2-way bank aliasing = free
    __shared__ int4   gi[64][17];

    const int Hs_[4] = {100, 50, 25, 13};
    const int S0_[4] = {0, 10000, 12500, 13125};

    int wb  = (blockIdx.x & 7) * DEF_CHUNK + (blockIdx.x >> 3);  // XCD-contiguous
    int g   = threadIdx.x >> 2;
    int j   = threadIdx.x & 3;
    int grp = wb * 64 + g;
    const int total = R_ROWS * NHEAD;
    if (grp >= total) grp = total - 1;   // clamp; duplicate writes are identical
    int h = grp & 7;
    int r = grp >> 3;
    int b = (r >= S_TOT) ? 1 : 0;
    int s = r - b * S_TOT;

    int lq = (s < 10000) ? 0 : (s < 12500) ? 1 : (s < 13125) ? 2 : 3;
    int t  = s - S0_[lq];
    int Wq = Hs_[lq];
    int iy = t / Wq;
    int jx = t - iy * Wq;
    float vx = vr[(b * NLVL + lq) * 2 + 0];
    float vy = vr[(b * NLVL + lq) * 2 + 1];
    float rx = (jx + 0.5f) / (vx * (float)Wq);
    float ry = (iy + 0.5f) / (vy * (float)Wq);

    const float* offp = off + (long)r * 256 + h * 32;
    float4 oa = ((const float4*)offp)[2 * j];
    float4 ob = ((const float4*)offp)[2 * j + 1];
    float4 lg = ((const float4*)(logits + (long)grp * 16))[j];

    float mx = fmaxf(fmaxf(lg.x, lg.y), fmaxf(lg.z, lg.w));
    mx = fmaxf(mx, __shfl_xor(mx, 1));
    mx = fmaxf(mx, __shfl_xor(mx, 2));
    float e0 = __expf(lg.x - mx), e1 = __expf(lg.y - mx);
    float e2 = __expf(lg.z - mx), e3 = __expf(lg.w - mx);
    float sum = e0 + e1 + e2 + e3;
    sum += __shfl_xor(sum, 1);
    sum += __shfl_xor(sum, 2);
    float inv = 1.f / sum;

    const int   H  = Hs_[j];
    const float fH = (float)H;
    const int   s0 = S0_[j];
    float oxs[4] = {oa.x, oa.z, ob.x, ob.z};
    float oys[4] = {oa.y, oa.w, ob.y, ob.w};
    float wts[4] = {e0 * inv, e1 * inv, e2 * inv, e3 * inv};
#pragma unroll
    for (int i = 0; i < 4; ++i) {
        float x = rx * fH + oxs[i] - 0.5f;
        float y = ry * fH + oys[i] - 0.5f;
        float xf = floorf(x), yf = floorf(y);
        float lx = x - xf, ly = y - yf;
        int x0 = (int)xf, y0 = (int)yf;
        bool xv0 = (x0 >= 0) & (x0 < H);
        bool xv1 = (x0 >= -1) & (x0 < H - 1);
        bool yv0 = (y0 >= 0) & (y0 < H);
        bool yv1 = (y0 >= -1) & (y0 < H - 1);
        float w = wts[i];
        float4 wv;
        wv.x = (xv0 & yv0) ? (1.f - lx) * (1.f - ly) * w : 0.f;
        wv.y = (xv1 & yv0) ? lx * (1.f - ly) * w : 0.f;
        wv.z = (xv0 & yv1) ? (1.f - lx) * ly * w : 0.f;
        wv.w = (xv1 & yv1) ? lx * ly * w : 0.f;
        int xc0 = min(max(x0, 0), H - 1), xc1 = min(max(x0 + 1, 0), H - 1);
        int yc0 = min(max(y0, 0), H - 1), yc1 = min(max(y0 + 1, 0), H - 1);
        int4 iv;
        iv.x = s0 + yc0 * H + xc0;
        iv.y = s0 + yc0 * H + xc1;
        iv.z = s0 + yc1 * H + xc0;
        iv.w = s0 + yc1 * H + xc1;
        gw[g][j * 4 + i] = wv;
        gi[g][j * 4 + i] = iv;
    }
    __syncthreads();

    const ushort_t* vb = v + ((long)b * S_TOT) * 256 + h * 32 + j * 8;
    f32x2 acc2[4];
#pragma unroll
    for (int c = 0; c < 4; ++c) acc2[c] = (f32x2)0.0f;

#define ACC_CORNER(IDX, WGT) do {                                            \
        uint4 gld = *(const uint4*)&vb[(long)(IDX) * 256];                   \
        unsigned uu0 = gld.x, uu1 = gld.y, uu2 = gld.z, uu3 = gld.w;         \
        f32x2 gv;                                                            \
        gv.x = __builtin_bit_cast(float, uu0 << 16);                         \
        gv.y = __builtin_bit_cast(float, uu0 & 0xFFFF0000u);                 \
        acc2[0] += gv * (WGT);                                               \
        gv.x = __builtin_bit_cast(float, uu1 << 16);                         \
        gv.y = __builtin_bit_cast(float, uu1 & 0xFFFF0000u);                 \
        acc2[1] += gv * (WGT);                                               \
        gv.x = __builtin_bit_cast(float, uu2 << 16);                         \
        gv.y = __builtin_bit_cast(float, uu2 & 0xFFFF0000u);                 \
        acc2[2] += gv * (WGT);                                               \
        gv.x = __builtin_bit_cast(float, uu3 << 16);                         \
        gv.y = __builtin_bit_cast(float, uu3 & 0xFFFF0000u);                 \
        acc2[3] += gv * (WGT);                                               \
    } while (0)

#pragma unroll 4
    for (int p = 0; p < 16; ++p) {
        float4 w = gw[g][p];
        int4   ix = gi[g][p];
        ACC_CORNER(ix.x, w.x);
        ACC_CORNER(ix.y, w.y);
        ACC_CORNER(ix.z, w.z);
        ACC_CORNER(ix.w, w.w);
    }
#undef ACC_CORNER

    uint4 o;
    o.x = (unsigned)f2bf(acc2[0].x) | ((unsigned)f2bf(acc2[0].y) << 16);
    o.y = (unsigned)f2bf(acc2[1].x) | ((unsigned)f2bf(acc2[1].y) << 16);
    o.z = (unsigned)f2bf(acc2[2].x) | ((unsigned)f2bf(acc2[2].y) << 16);
    o.w = (unsigned)f2bf(acc2[3].x) | ((unsigned)f2bf(acc2[3].y) << 16);
    *(uint4*)&out[(long)r * 256 + h * 32 + j * 8] = o;
}

// ---------------------------------------------------------------------------
// out = LayerNorm(a + b); one WAVE per row, float4 per lane, shuffle-only.
// grid = R_ROWS/4 (26588 = 4*6647 exactly).
// ---------------------------------------------------------------------------
template<bool DUAL>
__global__ __launch_bounds__(256) void add_ln_kernel(
    const float* __restrict__ a, const float* __restrict__ b,
    const float* __restrict__ g, const float* __restrict__ beta,
    float* __restrict__ outf, ushort_t* __restrict__ outb)
{
    int row  = blockIdx.x * 4 + (threadIdx.x >> 6);
    int lane = threadIdx.x & 63;
    long base = (long)row * 256 + lane * 4;
    float4 av = *(const float4*)&a[base];
    float4 bv = *(const float4*)&b[base];
    float4 x;
    x.x = av.x + bv.x; x.y = av.y + bv.y; x.z = av.z + bv.z; x.w = av.w + bv.w;
    float s1 = x.x + x.y + x.z + x.w;
    float s2 = x.x * x.x + x.y * x.y + x.z * x.z + x.w * x.w;
#pragma unroll
    for (int o = 1; o < 64; o <<= 1) {
        s1 += __shfl_xor(s1, o);
        s2 += __shfl_xor(s2, o);
    }
    float mean = s1 * (1.f / 256.f);
    float var  = s2 * (1.f / 256.f) - mean * mean;
    float inv  = rsqrtf(var + EPSF);
    float4 gv = *(const float4*)&g[lane * 4];
    float4 be = *(const float4*)&beta[lane * 4];
    float4 y;
    y.x = (x.x - mean) * inv * gv.x + be.x;
    y.y = (x.y - mean) * inv * gv.y + be.y;
    y.z = (x.z - mean) * inv * gv.z + be.z;
    y.w = (x.w - mean) * inv * gv.w + be.w;
    *(float4*)&outf[base] = y;
    if (DUAL) {
        uint2 o;
        o.x = (unsigned)f2bf(y.x) | ((unsigned)f2bf(y.y) << 16);
        o.y = (unsigned)f2bf(y.z) | ((unsigned)f2bf(y.w) << 16);
        *(uint2*)&outb[base] = o;
    }
}

// ---------------------------------------------------------------------------
extern "C" void kernel_launch(void* const* d_in, const int* in_sizes, int n_in,
                              void* d_out, int out_size, void* d_ws, size_t ws_size,
                              hipStream_t stream)
{
    const float* query  = (const float*)d_in[0];
    const float* qpos   = (const float*)d_in[1];
    const float* vr     = (const float*)d_in[2];
    const float* W_off  = (const float*)d_in[5];
    const float* b_off  = (const float*)d_in[6];
    const float* W_attn = (const float*)d_in[7];
    const float* b_attn = (const float*)d_in[8];
    const float* W_val  = (const float*)d_in[9];
    const float* b_val  = (const float*)d_in[10];
    const float* W_out  = (const float*)d_in[11];
    const float* b_out  = (const float*)d_in[12];
    const float* ln1g   = (const float*)d_in[13];
    const float* ln1b   = (const float*)d_in[14];
    const float* W1     = (const float*)d_in[15];
    const float* b1     = (const float*)d_in[16];
    const float* W2     = (const float*)d_in[17];
    const float* b2     = (const float*)d_in[18];
    const float* ln2g   = (const float*)d_in[19];
    const float* ln2b   = (const float*)d_in[20];
    float* out = (float*)d_out;

    float* ws = (float*)d_ws;
    const long R128 = (long)R_ROWS * 128;
    ushort_t* q_bf    = (ushort_t*)(ws);                 // R x 256 bf16
    ushort_t* qry_bf  = (ushort_t*)(ws + R128);          // R x 256 bf16
    ushort_t* v_bf    = (ushort_t*)(ws + 2 * R128);      // R x 256 bf16
    float*    logits  = ws + 3 * R128;                   // R x 128 f32
    ushort_t* h_bf    = (ushort_t*)(ws);                 // R x 1024 bf16 (overlays the 4 above)
    float*    cb      = ws + 4 * R128;                   // R x 256 f32: off -> attn_out -> f
    ushort_t* samp_bf = (ushort_t*)(ws + 6 * R128);      // R x 256 bf16: sampled -> x_bf
    float*    xb      = ws + 7 * R128;                   // R x 256 f32: x (LN1 out)
    ushort_t* wt      = (ushort_t*)(ws + 9 * R128);
    ushort_t* wt_val  = wt;                 // 256x256
    ushort_t* wt_off  = wt + 65536;         // 256x256
    ushort_t* wt_attn = wt + 131072;        // 128x256
    ushort_t* wt_out  = wt + 163840;        // 256x256
    ushort_t* wt_w1   = wt + 229376;        // 1024x256
    ushort_t* wt_w2   = wt + 491520;        // 256x1024

    dim3 blk(256);
    const int MB128 = (R_ROWS + 127) / 128;   // 208
    const int MB64  = (R_ROWS + 63) / 64;     // 416

    transpose_all_kernel<<<736, blk, 0, stream>>>(
        W_val, W_off, W_attn, W_out, W1, W2,
        wt_val, wt_off, wt_attn, wt_out, wt_w1, wt_w2);
    addcvt_kernel<<<(R_ROWS * 64 + 255) / 256, blk, 0, stream>>>(
        query, qpos, qry_bf, q_bf, R_ROWS * 64);
    proj_kernel<<<dim3(MB128, 5), blk, 0, stream>>>(
        qry_bf, q_bf, wt_val, wt_off, wt_attn, b_val, b_off, b_attn,
        v_bf, cb, logits);
    deform_sample_kernel<<<DEF_BLOCKS, blk, 0, stream>>>(
        v_bf, cb, logits, vr, samp_bf);
    gemm_mfma_kernel<64, false, false><<<dim3(MB64, 2), blk, 0, stream>>>(
        samp_bf, wt_out, b_out, cb, R_ROWS, 256, 256);
    add_ln_kernel<true><<<R_ROWS / 4, blk, 0, stream>>>(
        query, cb, ln1g, ln1b, xb, samp_bf);
    gemm_mfma_kernel<128, true, true><<<dim3(MB128, 8), blk, 0, stream>>>(
        samp_bf, wt_w1, b1, h_bf, R_ROWS, 1024, 256);
    gemm_mfma_kernel<64, false, false><<<dim3(MB64, 2), blk, 0, stream>>>(
        h_bf, wt_w2, b2, cb, R_ROWS, 256, 1024);
    add_ln_kernel<false><<<R_ROWS / 4, blk, 0, stream>>>(
        xb, cb, ln2g, ln2b, out, nullptr);
}

// Round 8
// 318.015 us; speedup vs baseline: 1.0377x; 1.0377x over previous
//
#include <hip/hip_runtime.h>
#include <math.h>

#define R_ROWS 26588
#define S_TOT  13294
#define NHEAD  8
#define NLVL   4
#define EPSF   1e-5f

typedef __attribute__((ext_vector_type(8))) short short8;
typedef __attribute__((ext_vector_type(4))) float f32x4;
typedef __attribute__((ext_vector_type(2))) float f32x2;
typedef unsigned short ushort_t;

__device__ __forceinline__ unsigned short f2bf(float f) {
    unsigned int u = __builtin_bit_cast(unsigned int, f);
    unsigned int r = (u + 0x7FFFu + ((u >> 16) & 1u)) >> 16;   // RNE
    return (unsigned short)r;
}

// ---------------------------------------------------------------------------
// Prep: all six weight transposes (blocks 0..735) + query add/convert
// (blocks 736..7382) in ONE launch.
// ---------------------------------------------------------------------------
__global__ __launch_bounds__(256) void prep_kernel(
    const float* __restrict__ W_val, const float* __restrict__ W_off,
    const float* __restrict__ W_attn, const float* __restrict__ W_out,
    const float* __restrict__ W1, const float* __restrict__ W2,
    ushort_t* __restrict__ wt_val, ushort_t* __restrict__ wt_off,
    ushort_t* __restrict__ wt_attn, ushort_t* __restrict__ wt_out,
    ushort_t* __restrict__ wt_w1, ushort_t* __restrict__ wt_w2,
    const float* __restrict__ query, const float* __restrict__ qpos,
    ushort_t* __restrict__ qry_bf, ushort_t* __restrict__ qsum_bf)
{
    __shared__ ushort_t tt[32][33];
    int bid = blockIdx.x;
    if (bid < 736) {
        const float* src; ushort_t* dst; int K, N, t;
        if (bid < 64)       { src = W_val;  dst = wt_val;  K = 256;  N = 256;  t = bid; }
        else if (bid < 128) { src = W_off;  dst = wt_off;  K = 256;  N = 256;  t = bid - 64; }
        else if (bid < 160) { src = W_attn; dst = wt_attn; K = 256;  N = 128;  t = bid - 128; }
        else if (bid < 224) { src = W_out;  dst = wt_out;  K = 256;  N = 256;  t = bid - 160; }
        else if (bid < 480) { src = W1;     dst = wt_w1;   K = 256;  N = 1024; t = bid - 224; }
        else                { src = W2;     dst = wt_w2;   K = 1024; N = 256;  t = bid - 480; }
        int nt = N / 32;
        int bn = (t % nt) * 32, bk = (t / nt) * 32;
        int x = threadIdx.x & 31;
        int y = threadIdx.x >> 5;
#pragma unroll
        for (int i = 0; i < 4; ++i) {
            int k = y + i * 8;
            tt[x][k] = f2bf(src[(long)(bk + k) * N + bn + x]);
        }
        __syncthreads();
#pragma unroll
        for (int i = 0; i < 4; ++i) {
            int n = y + i * 8;
            dst[(long)(bn + n) * K + bk + x] = tt[n][x];
        }
    } else {
        int i = (bid - 736) * 256 + threadIdx.x;   // < R_ROWS*64 exactly
        float4 a = ((const float4*)query)[i];
        float4 b = ((const float4*)qpos)[i];
        uint2 qa, qs;
        qa.x = (unsigned)f2bf(a.x) | ((unsigned)f2bf(a.y) << 16);
        qa.y = (unsigned)f2bf(a.z) | ((unsigned)f2bf(a.w) << 16);
        qs.x = (unsigned)f2bf(a.x + b.x) | ((unsigned)f2bf(a.y + b.y) << 16);
        qs.y = (unsigned)f2bf(a.z + b.z) | ((unsigned)f2bf(a.w + b.w) << 16);
        ((uint2*)qry_bf)[i] = qa;
        ((uint2*)qsum_bf)[i] = qs;
    }
}

// ---------------------------------------------------------------------------
// Async triple-buffered GEMM core, 128x128 tile, BK=32 (for proj + ffn1).
// ---------------------------------------------------------------------------
__device__ __forceinline__ void stage_ab(
    const ushort_t* __restrict__ Arow, const ushort_t* __restrict__ Brow,
    int K, int k0, ushort_t* As, ushort_t* Bs, int wave, int lane)
{
    int quadS = lane & 3;
    int rr = lane >> 2;
#pragma unroll
    for (int inst = 0; inst < 2; ++inst) {
        int base_row = wave * 32 + inst * 16;
        int r = base_row + rr;
        int quadG = quadS ^ ((r >> 1) & 3);
        const ushort_t* gp = Arow + (long)r * K + k0 + quadG * 8;
        __builtin_amdgcn_global_load_lds(
            (const __attribute__((address_space(1))) unsigned int*)gp,
            (__attribute__((address_space(3))) unsigned int*)&As[base_row * 32],
            16, 0, 0);
    }
#pragma unroll
    for (int inst = 0; inst < 2; ++inst) {
        int base_row = wave * 32 + inst * 16;
        int r = base_row + rr;
        int quadG = quadS ^ ((r >> 1) & 3);
        const ushort_t* gp = Brow + (long)r * K + k0 + quadG * 8;
        __builtin_amdgcn_global_load_lds(
            (const __attribute__((address_space(1))) unsigned int*)gp,
            (__attribute__((address_space(3))) unsigned int*)&Bs[base_row * 32],
            16, 0, 0);
    }
}

__device__ __forceinline__ void gemm_body(
    ushort_t* As, ushort_t* Bs,   // flat [3*4096] each
    const ushort_t* __restrict__ A, const ushort_t* __restrict__ Wt,
    const float* __restrict__ bias, void* __restrict__ Cv,
    int M, int N, int K, int bm, int bn, bool out_bf16, bool relu)
{
    const int tid  = threadIdx.x;
    const int wave = tid >> 6;
    const int lane = tid & 63;
    const int l15  = lane & 15;
    const int quad = lane >> 4;
    const int wm   = (wave >> 1) * 64;
    const int wn   = (wave & 1) * 64;

    const ushort_t* Arow = A + (long)bm * K;
    const ushort_t* Brow = Wt + (long)bn * K;

    f32x4 acc[4][4];
#pragma unroll
    for (int i = 0; i < 4; ++i)
#pragma unroll
        for (int j = 0; j < 4; ++j) acc[i][j] = (f32x4)0.0f;

    int aoff[4], boff[4];
#pragma unroll
    for (int mi = 0; mi < 4; ++mi) {
        int r = wm + mi * 16 + l15;
        aoff[mi] = r * 32 + (quad ^ ((r >> 1) & 3)) * 8;
    }
#pragma unroll
    for (int ni = 0; ni < 4; ++ni) {
        int r = wn + ni * 16 + l15;
        boff[ni] = r * 32 + (quad ^ ((r >> 1) & 3)) * 8;
    }

    const int NT = K >> 5;
    stage_ab(Arow, Brow, K, 0, As, Bs, wave, lane);
    int cur = 0;
    for (int t = 0; t < NT; ++t) {
        int nxt = cur + 1; if (nxt == 3) nxt = 0;
        if (t + 1 < NT) {
            stage_ab(Arow, Brow, K, (t + 1) << 5,
                     As + nxt * 4096, Bs + nxt * 4096, wave, lane);
            asm volatile("s_waitcnt vmcnt(4)" ::: "memory");
        } else {
            asm volatile("s_waitcnt vmcnt(0)" ::: "memory");
        }
        asm volatile("s_barrier" ::: "memory");

        const ushort_t* Ab = As + cur * 4096;
        const ushort_t* Bb = Bs + cur * 4096;
        short8 af[4], bf[4];
#pragma unroll
        for (int mi = 0; mi < 4; ++mi) af[mi] = *(const short8*)&Ab[aoff[mi]];
#pragma unroll
        for (int ni = 0; ni < 4; ++ni) bf[ni] = *(const short8*)&Bb[boff[ni]];
#pragma unroll
        for (int mi = 0; mi < 4; ++mi)
#pragma unroll
            for (int ni = 0; ni < 4; ++ni)
                acc[mi][ni] = __builtin_amdgcn_mfma_f32_16x16x32_bf16(
                    af[mi], bf[ni], acc[mi][ni], 0, 0, 0);
        cur = nxt;
    }

#pragma unroll
    for (int mi = 0; mi < 4; ++mi) {
#pragma unroll
        for (int r = 0; r < 4; ++r) {
            int row = bm + wm + mi * 16 + quad * 4 + r;
            if (row >= M) continue;
#pragma unroll
            for (int ni = 0; ni < 4; ++ni) {
                int col = bn + wn + ni * 16 + l15;
                float vv = acc[mi][ni][r] + bias[col];
                if (relu) vv = fmaxf(vv, 0.f);
                if (out_bf16)
                    ((ushort_t*)Cv)[(long)row * N + col] = f2bf(vv);
                else
                    ((float*)Cv)[(long)row * N + col] = vv;
            }
        }
    }
}

template<bool OUT_BF16, bool RELU>
__global__ __launch_bounds__(256) void gemm_mfma_kernel(
    const ushort_t* __restrict__ A, const ushort_t* __restrict__ Wt,
    const float* __restrict__ bias, void* __restrict__ Cv,
    int M, int N, int K)
{
    __shared__ ushort_t As[3 * 4096];
    __shared__ ushort_t Bs[3 * 4096];
    gemm_body(As, Bs, A, Wt, bias, Cv, M, N, K,
              blockIdx.x * 128, blockIdx.y * 128, OUT_BF16, RELU);
}

// Combined val/off/attn projections. grid = (208, 5).
__global__ __launch_bounds__(256) void proj_kernel(
    const ushort_t* __restrict__ qry_bf, const ushort_t* __restrict__ q_bf,
    const ushort_t* __restrict__ wt_val, const ushort_t* __restrict__ wt_off,
    const ushort_t* __restrict__ wt_attn,
    const float* __restrict__ b_val, const float* __restrict__ b_off,
    const float* __restrict__ b_attn,
    ushort_t* __restrict__ v_bf, float* __restrict__ cb, float* __restrict__ logits)
{
    __shared__ ushort_t As[3 * 4096];
    __shared__ ushort_t Bs[3 * 4096];
    int y = blockIdx.y;
    const ushort_t* A; const ushort_t* Wt; const float* bias;
    void* C; bool outbf; int N, bn;
    if (y < 2)      { A = qry_bf; Wt = wt_val;  bias = b_val;  C = v_bf;   outbf = true;  N = 256; bn = y * 128; }
    else if (y < 4) { A = q_bf;   Wt = wt_off;  bias = b_off;  C = cb;     outbf = false; N = 256; bn = (y - 2) * 128; }
    else            { A = q_bf;   Wt = wt_attn; bias = b_attn; C = logits; outbf = false; N = 128; bn = 0; }
    gemm_body(As, Bs, A, Wt, bias, C, R_ROWS, N, 256, blockIdx.x * 128, bn, outbf, false);
}

// ---------------------------------------------------------------------------
// Fused GEMM (32 rows x full N=256, bf16 A, Wt [256][K]) + residual + LayerNorm.
// outf = LN(resid + A@Wt^T + bias); DUAL also writes bf16 copy.
// 4 waves: wave w owns cols w*64..w*64+63, all 32 rows. Triple-buffered DMA.
// ---------------------------------------------------------------------------
__device__ __forceinline__ void stage_ln(
    const ushort_t* __restrict__ Arow, const ushort_t* __restrict__ Brow,
    int K, int k0, ushort_t* As, ushort_t* Bs, int wave, int lane)
{
    int quadS = lane & 3;
    int rr = lane >> 2;
    if (wave < 2) {      // A tile: 32 rows = 2 insts (waves 0,1)
        int base_row = wave * 16;
        int r = base_row + rr;
        int quadG = quadS ^ ((r >> 1) & 3);
        const ushort_t* gp = Arow + (long)r * K + k0 + quadG * 8;
        __builtin_amdgcn_global_load_lds(
            (const __attribute__((address_space(1))) unsigned int*)gp,
            (__attribute__((address_space(3))) unsigned int*)&As[base_row * 32],
            16, 0, 0);
    }
#pragma unroll
    for (int inst = 0; inst < 4; ++inst) {   // B tile: 256 rows, wave stages own slab
        int base_row = wave * 64 + inst * 16;
        int r = base_row + rr;
        int quadG = quadS ^ ((r >> 1) & 3);
        const ushort_t* gp = Brow + (long)r * K + k0 + quadG * 8;
        __builtin_amdgcn_global_load_lds(
            (const __attribute__((address_space(1))) unsigned int*)gp,
            (__attribute__((address_space(3))) unsigned int*)&Bs[base_row * 32],
            16, 0, 0);
    }
}

template<bool DUAL>
__global__ __launch_bounds__(256) void gemm_ln_kernel(
    const ushort_t* __restrict__ A, const ushort_t* __restrict__ Wt,
    const float* __restrict__ bias, const float* __restrict__ resid,
    const float* __restrict__ gam, const float* __restrict__ bet,
    float* __restrict__ outf, ushort_t* __restrict__ outb,
    int M, int K)
{
    __shared__ ushort_t As[3 * 1024];
    __shared__ ushort_t Bs[3 * 8192];
    __shared__ float s1s[32][4], s2s[32][4];

    const int tid  = threadIdx.x;
    const int wave = tid >> 6;
    const int lane = tid & 63;
    const int l15  = lane & 15;
    const int quad = lane >> 4;
    const int wn   = wave * 64;
    const int bm   = blockIdx.x * 32;

    const ushort_t* Arow = A + (long)bm * K;

    // prefetch residual + per-col params (overlaps with staging)
    float bias4[4], g4[4], be4[4];
#pragma unroll
    for (int ni = 0; ni < 4; ++ni) {
        int col = wn + ni * 16 + l15;
        bias4[ni] = bias[col];
        g4[ni]    = gam[col];
        be4[ni]   = bet[col];
    }
    float rv[2][4][4];
#pragma unroll
    for (int mi = 0; mi < 2; ++mi)
#pragma unroll
        for (int rr = 0; rr < 4; ++rr) {
            int row = bm + mi * 16 + quad * 4 + rr;
#pragma unroll
            for (int ni = 0; ni < 4; ++ni) {
                int col = wn + ni * 16 + l15;
                rv[mi][rr][ni] = (row < M) ? resid[(long)row * 256 + col] : 0.f;
            }
        }

    f32x4 acc[2][4];
#pragma unroll
    for (int i = 0; i < 2; ++i)
#pragma unroll
        for (int j = 0; j < 4; ++j) acc[i][j] = (f32x4)0.0f;

    int aoff[2], boff[4];
#pragma unroll
    for (int mi = 0; mi < 2; ++mi) {
        int r = mi * 16 + l15;
        aoff[mi] = r * 32 + (quad ^ ((r >> 1) & 3)) * 8;
    }
#pragma unroll
    for (int ni = 0; ni < 4; ++ni) {
        int r = wn + ni * 16 + l15;
        boff[ni] = r * 32 + (quad ^ ((r >> 1) & 3)) * 8;
    }

    const int NT = K >> 5;
    stage_ln(Arow, Wt, K, 0, As, Bs, wave, lane);
    int cur = 0;
    for (int t = 0; t < NT; ++t) {
        int nxt = cur + 1; if (nxt == 3) nxt = 0;
        if (t + 1 < NT) {
            stage_ln(Arow, Wt, K, (t + 1) << 5,
                     As + nxt * 1024, Bs + nxt * 8192, wave, lane);
            asm volatile("s_waitcnt vmcnt(4)" ::: "memory");  // safe for 4- or 5-issue waves
        } else {
            asm volatile("s_waitcnt vmcnt(0)" ::: "memory");
        }
        asm volatile("s_barrier" ::: "memory");

        const ushort_t* Ab = As + cur * 1024;
        const ushort_t* Bb = Bs + cur * 8192;
        short8 af[2], bf[4];
#pragma unroll
        for (int mi = 0; mi < 2; ++mi) af[mi] = *(const short8*)&Ab[aoff[mi]];
#pragma unroll
        for (int ni = 0; ni < 4; ++ni) bf[ni] = *(const short8*)&Bb[boff[ni]];
#pragma unroll
        for (int mi = 0; mi < 2; ++mi)
#pragma unroll
            for (int ni = 0; ni < 4; ++ni)
                acc[mi][ni] = __builtin_amdgcn_mfma_f32_16x16x32_bf16(
                    af[mi], bf[ni], acc[mi][ni], 0, 0, 0);
        cur = nxt;
    }

    // ---- epilogue: x = acc + bias + resid; LN over the 256-col rows ----
#pragma unroll
    for (int mi = 0; mi < 2; ++mi)
#pragma unroll
        for (int rr = 0; rr < 4; ++rr) {
            float s1 = 0.f, s2 = 0.f;
#pragma unroll
            for (int ni = 0; ni < 4; ++ni) {
                float x = acc[mi][ni][rr] + bias4[ni] + rv[mi][rr][ni];
                acc[mi][ni][rr] = x;
                s1 += x; s2 += x * x;
            }
#pragma unroll
            for (int o = 1; o < 16; o <<= 1) {
                s1 += __shfl_xor(s1, o);
                s2 += __shfl_xor(s2, o);
            }
            if (l15 == 0) {
                int rl = mi * 16 + quad * 4 + rr;
                s1s[rl][wave] = s1;
                s2s[rl][wave] = s2;
            }
        }
    __syncthreads();
#pragma unroll
    for (int mi = 0; mi < 2; ++mi)
#pragma unroll
        for (int rr = 0; rr < 4; ++rr) {
            int rl  = mi * 16 + quad * 4 + rr;
            int row = bm + rl;
            float t1 = s1s[rl][0] + s1s[rl][1] + s1s[rl][2] + s1s[rl][3];
            float t2 = s2s[rl][0] + s2s[rl][1] + s2s[rl][2] + s2s[rl][3];
            float mean = t1 * (1.f / 256.f);
            float var  = t2 * (1.f / 256.f) - mean * mean;
            float inv  = rsqrtf(var + EPSF);
            if (row < M) {
#pragma unroll
                for (int ni = 0; ni < 4; ++ni) {
                    int col = wn + ni * 16 + l15;
                    float y = (acc[mi][ni][rr] - mean) * inv * g4[ni] + be4[ni];
                    outf[(long)row * 256 + col] = y;
                    if (DUAL) outb[(long)row * 256 + col] = f2bf(y);
                }
            }
        }
}

// ---------------------------------------------------------------------------
// Deformable sampling + fused softmax (R5 version: shfl broadcast, XCD swizzle)
// ---------------------------------------------------------------------------
#define DEF_BLOCKS 3328
#define DEF_CHUNK  416

__global__ __launch_bounds__(256) void deform_sample_kernel(
    const ushort_t* __restrict__ v, const float* __restrict__ off,
    const float* __restrict__ logits, const float* __restrict__ vr,
    ushort_t* __restrict__ out)
{
    const int Hs_[4] = {100, 50, 25, 13};
    const int S0_[4] = {0, 10000, 12500, 13125};

    int wb  = (blockIdx.x & 7) * DEF_CHUNK + (blockIdx.x >> 3);
    int grp = wb * 64 + (threadIdx.x >> 2);
    int j   = threadIdx.x & 3;
    if (grp >= R_ROWS * NHEAD) return;
    int h = grp & 7;
    int r = grp >> 3;
    int b = (r >= S_TOT) ? 1 : 0;
    int s = r - b * S_TOT;

    int lq = (s < 10000) ? 0 : (s < 12500) ? 1 : (s < 13125) ? 2 : 3;
    int t  = s - S0_[lq];
    int Wq = Hs_[lq];
    int iy = t / Wq;
    int jx = t - iy * Wq;
    float vx = vr[(b * NLVL + lq) * 2 + 0];
    float vy = vr[(b * NLVL + lq) * 2 + 1];
    float rx = (jx + 0.5f) / (vx * (float)Wq);
    float ry = (iy + 0.5f) / (vy * (float)Wq);

    const float* offp = off + (long)r * 256 + h * 32;
    float4 oa = ((const float4*)offp)[2 * j];
    float4 ob = ((const float4*)offp)[2 * j + 1];
    float4 lg = ((const float4*)(logits + (long)grp * 16))[j];

    float mx = fmaxf(fmaxf(lg.x, lg.y), fmaxf(lg.z, lg.w));
    mx = fmaxf(mx, __shfl_xor(mx, 1));
    mx = fmaxf(mx, __shfl_xor(mx, 2));
    float e0 = __expf(lg.x - mx), e1 = __expf(lg.y - mx);
    float e2 = __expf(lg.z - mx), e3 = __expf(lg.w - mx);
    float sum = e0 + e1 + e2 + e3;
    sum += __shfl_xor(sum, 1);
    sum += __shfl_xor(sum, 2);
    float inv = 1.f / sum;

    const int   H  = Hs_[j];
    const float fH = (float)H;
    const int   s0 = S0_[j];
    float oxs[4] = {oa.x, oa.z, ob.x, ob.z};
    float oys[4] = {oa.y, oa.w, ob.y, ob.w};
    float wts[4] = {e0 * inv, e1 * inv, e2 * inv, e3 * inv};
    float pw0[4], pw1[4], pw2[4], pw3[4];
    int   pi0[4], pi1[4], pi2[4], pi3[4];
#pragma unroll
    for (int i = 0; i < 4; ++i) {
        float x = rx * fH + oxs[i] - 0.5f;
        float y = ry * fH + oys[i] - 0.5f;
        float xf = floorf(x), yf = floorf(y);
        float lx = x - xf, ly = y - yf;
        int x0 = (int)xf, y0 = (int)yf;
        bool xv0 = (x0 >= 0) & (x0 < H);
        bool xv1 = (x0 >= -1) & (x0 < H - 1);
        bool yv0 = (y0 >= 0) & (y0 < H);
        bool yv1 = (y0 >= -1) & (y0 < H - 1);
        float w = wts[i];
        pw0[i] = (xv0 & yv0) ? (1.f - lx) * (1.f - ly) * w : 0.f;
        pw1[i] = (xv1 & yv0) ? lx * (1.f - ly) * w : 0.f;
        pw2[i] = (xv0 & yv1) ? (1.f - lx) * ly * w : 0.f;
        pw3[i] = (xv1 & yv1) ? lx * ly * w : 0.f;
        int xc0 = min(max(x0, 0), H - 1), xc1 = min(max(x0 + 1, 0), H - 1);
        int yc0 = min(max(y0, 0), H - 1), yc1 = min(max(y0 + 1, 0), H - 1);
        pi0[i] = s0 + yc0 * H + xc0;
        pi1[i] = s0 + yc0 * H + xc1;
        pi2[i] = s0 + yc1 * H + xc0;
        pi3[i] = s0 + yc1 * H + xc1;
    }

    const ushort_t* vb = v + ((long)b * S_TOT) * 256 + h * 32 + j * 8;
    f32x2 acc2[4];
#pragma unroll
    for (int c = 0; c < 4; ++c) acc2[c] = (f32x2)0.0f;

#define ACC_CORNER(IDX, WGT) do {                                            \
        uint4 g = *(const uint4*)&vb[(long)(IDX) * 256];                     \
        unsigned uu0 = g.x, uu1 = g.y, uu2 = g.z, uu3 = g.w;                 \
        f32x2 gv;                                                            \
        gv.x = __builtin_bit_cast(float, uu0 << 16);                         \
        gv.y = __builtin_bit_cast(float, uu0 & 0xFFFF0000u);                 \
        acc2[0] += gv * (WGT);                                               \
        gv.x = __builtin_bit_cast(float, uu1 << 16);                         \
        gv.y = __builtin_bit_cast(float, uu1 & 0xFFFF0000u);                 \
        acc2[1] += gv * (WGT);                                               \
        gv.x = __builtin_bit_cast(float, uu2 << 16);                         \
        gv.y = __builtin_bit_cast(float, uu2 & 0xFFFF0000u);                 \
        acc2[2] += gv * (WGT);                                               \
        gv.x = __builtin_bit_cast(float, uu3 << 16);                         \
        gv.y = __builtin_bit_cast(float, uu3 & 0xFFFF0000u);                 \
        acc2[3] += gv * (WGT);                                               \
    } while (0)

#pragma unroll
    for (int i = 0; i < 4; ++i) {
#pragma unroll
        for (int j2 = 0; j2 < 4; ++j2) {
            float w00 = __shfl(pw0[i], j2, 4);
            float w01 = __shfl(pw1[i], j2, 4);
            float w10 = __shfl(pw2[i], j2, 4);
            float w11 = __shfl(pw3[i], j2, 4);
            int   i00 = __shfl(pi0[i], j2, 4);
            int   i01 = __shfl(pi1[i], j2, 4);
            int   i10 = __shfl(pi2[i], j2, 4);
            int   i11 = __shfl(pi3[i], j2, 4);
            ACC_CORNER(i00, w00);
            ACC_CORNER(i01, w01);
            ACC_CORNER(i10, w10);
            ACC_CORNER(i11, w11);
        }
    }
#undef ACC_CORNER

    uint4 o;
    o.x = (unsigned)f2bf(acc2[0].x) | ((unsigned)f2bf(acc2[0].y) << 16);
    o.y = (unsigned)f2bf(acc2[1].x) | ((unsigned)f2bf(acc2[1].y) << 16);
    o.z = (unsigned)f2bf(acc2[2].x) | ((unsigned)f2bf(acc2[2].y) << 16);
    o.w = (unsigned)f2bf(acc2[3].x) | ((unsigned)f2bf(acc2[3].y) << 16);
    *(uint4*)&out[(long)r * 256 + h * 32 + j * 8] = o;
}

// ---------------------------------------------------------------------------
extern "C" void kernel_launch(void* const* d_in, const int* in_sizes, int n_in,
                              void* d_out, int out_size, void* d_ws, size_t ws_size,
                              hipStream_t stream)
{
    const float* query  = (const float*)d_in[0];
    const float* qpos   = (const float*)d_in[1];
    const float* vr     = (const float*)d_in[2];
    const float* W_off  = (const float*)d_in[5];
    const float* b_off  = (const float*)d_in[6];
    const float* W_attn = (const float*)d_in[7];
    const float* b_attn = (const float*)d_in[8];
    const float* W_val  = (const float*)d_in[9];
    const float* b_val  = (const float*)d_in[10];
    const float* W_out  = (const float*)d_in[11];
    const float* b_out  = (const float*)d_in[12];
    const float* ln1g   = (const float*)d_in[13];
    const float* ln1b   = (const float*)d_in[14];
    const float* W1     = (const float*)d_in[15];
    const float* b1     = (const float*)d_in[16];
    const float* W2     = (const float*)d_in[17];
    const float* b2     = (const float*)d_in[18];
    const float* ln2g   = (const float*)d_in[19];
    const float* ln2b   = (const float*)d_in[20];
    float* out = (float*)d_out;

    float* ws = (float*)d_ws;
    const long R128 = (long)R_ROWS * 128;
    ushort_t* q_bf    = (ushort_t*)(ws);                 // R x 256 bf16
    ushort_t* qry_bf  = (ushort_t*)(ws + R128);          // R x 256 bf16
    ushort_t* v_bf    = (ushort_t*)(ws + 2 * R128);      // R x 256 bf16
    float*    logits  = ws + 3 * R128;                   // R x 128 f32
    ushort_t* h_bf    = (ushort_t*)(ws);                 // R x 1024 bf16 (overlays above, FF stage)
    float*    cb      = ws + 4 * R128;                   // R x 256 f32: off
    ushort_t* samp_bf = (ushort_t*)(ws + 6 * R128);      // R x 256 bf16: sampled -> x_bf
    float*    xb      = ws + 7 * R128;                   // R x 256 f32: x (LN1 out)
    ushort_t* wt      = (ushort_t*)(ws + 9 * R128);
    ushort_t* wt_val  = wt;                 // 256x256
    ushort_t* wt_off  = wt + 65536;         // 256x256
    ushort_t* wt_attn = wt + 131072;        // 128x256
    ushort_t* wt_out  = wt + 163840;        // 256x256
    ushort_t* wt_w1   = wt + 229376;        // 1024x256
    ushort_t* wt_w2   = wt + 491520;        // 256x1024

    dim3 blk(256);
    const int MB128 = (R_ROWS + 127) / 128;   // 208
    const int MB32  = (R_ROWS + 31) / 32;     // 831

    // 1. prep: weight transposes + q/qsum bf16 conversion
    prep_kernel<<<736 + R_ROWS / 4, blk, 0, stream>>>(
        W_val, W_off, W_attn, W_out, W1, W2,
        wt_val, wt_off, wt_attn, wt_out, wt_w1, wt_w2,
        query, qpos, qry_bf, q_bf);
    // 2. val + off + attn projections
    proj_kernel<<<dim3(MB128, 5), blk, 0, stream>>>(
        qry_bf, q_bf, wt_val, wt_off, wt_attn, b_val, b_off, b_attn,
        v_bf, cb, logits);
    // 3. deformable sampling (+softmax) -> samp_bf
    deform_sample_kernel<<<DEF_BLOCKS, blk, 0, stream>>>(
        v_bf, cb, logits, vr, samp_bf);
    // 4. x = LN(query + samp @ W_out + b_out) -> xb (f32) + samp_bf (bf16)
    gemm_ln_kernel<true><<<MB32, blk, 0, stream>>>(
        samp_bf, wt_out, b_out, query, ln1g, ln1b, xb, samp_bf, R_ROWS, 256);
    // 5. h = relu(x @ W1 + b1) -> h_bf
    gemm_mfma_kernel<true, true><<<dim3(MB128, 8), blk, 0, stream>>>(
        samp_bf, wt_w1, b1, h_bf, R_ROWS, 1024, 256);
    // 6. out = LN(x + h @ W2 + b2)
    gemm_ln_kernel<false><<<MB32, blk, 0, stream>>>(
        h_bf, wt_w2, b2, xb, ln2g, ln2b, out, nullptr, R_ROWS, 1024);
}